// Round 11
// baseline (3251.975 us; speedup 1.0000x reference)
//
#include <hip/hip_runtime.h>
#include <hip/hip_bf16.h>

#define N 4096
#define B 8
#define ITERS 10
#define T (ITERS * N)
#define NT 256          // 4 waves
#define E 16            // field elements per thread
#define WIN 1024
#define INFK 0xFFFFFFFFu
#define LIMIT 0x01000000u

// Bare workgroup barrier: waits LDS ops only (lgkmcnt), NOT vmem.
// __syncthreads would emit s_waitcnt vmcnt(0) and drain our in-flight row
// prefetches every round (the m97 stall); our inter-wave exchange is pure
// LDS, so lgkmcnt(0)+s_barrier is sufficient for the slot handoff.
// Parity-double-buffered slots bound wave skew to one round.
#define BAR_LDS() asm volatile("s_waitcnt lgkmcnt(0)\n\ts_barrier" ::: "memory")

// Kernel 1: Z0[b][i] = sum_j W[i][j] * x[b][j], accumulated in double.
// UNCHANGED (decision-identical trajectory vs rounds 1-10).
__global__ __launch_bounds__(256) void z0_gemv(const float* __restrict__ W,
                                               const float* __restrict__ x,
                                               double* __restrict__ Z0) {
    const int i = blockIdx.x;
    const int tid = threadIdx.x;
    const float* __restrict__ row = W + (size_t)i * N;

    double acc[B];
#pragma unroll
    for (int b = 0; b < B; ++b) acc[b] = 0.0;

    for (int j = tid; j < N; j += 256) {
        const double w = (double)row[j];
#pragma unroll
        for (int b = 0; b < B; ++b) acc[b] += w * (double)x[b * N + j];
    }

    __shared__ double red[256 * B];  // 16 KB
#pragma unroll
    for (int b = 0; b < B; ++b) red[tid * B + b] = acc[b];
    __syncthreads();

    for (int s = 128; s > 0; s >>= 1) {
        if (tid < s) {
#pragma unroll
            for (int b = 0; b < B; ++b) red[tid * B + b] += red[(tid + s) * B + b];
        }
        __syncthreads();
    }
    if (tid < B) Z0[(size_t)tid * N + i] = red[tid];
}

__device__ __forceinline__ unsigned umin2(unsigned a, unsigned b) { return a < b ? a : b; }

template <int CTRL>
__device__ __forceinline__ unsigned dpp_min(unsigned v) {
    const int t = __builtin_amdgcn_update_dpp((int)v, (int)v, CTRL, 0xF, 0xF, false);
    return umin2(v, (unsigned)t);
}

// Full wave64 min via DPP; wave-uniform result via readlane(63).
__device__ __forceinline__ unsigned wave_min64(unsigned v) {
    v = dpp_min<0x111>(v);  // row_shr:1
    v = dpp_min<0x112>(v);  // row_shr:2
    v = dpp_min<0x114>(v);  // row_shr:4
    v = dpp_min<0x118>(v);  // row_shr:8
    v = dpp_min<0x142>(v);  // row_bcast:15
    v = dpp_min<0x143>(v);  // row_bcast:31
    return (unsigned)__builtin_amdgcn_readlane((int)v, 63);
}

__device__ __forceinline__ void copy16(float* dst, const float* src) {
#pragma unroll
    for (int k = 0; k < E; ++k) dst[k] = src[k];
}

__device__ __forceinline__ void load_row(const float* __restrict__ W, int idx, int tid, float* dst) {
    const float4* __restrict__ rp = (const float4*)(W + (size_t)idx * N) + 4 * tid;
    const float4 a = rp[0], c = rp[1], e = rp[2], f = rp[3];
    dst[0] = a.x;  dst[1] = a.y;  dst[2] = a.z;  dst[3] = a.w;
    dst[4] = c.x;  dst[5] = c.y;  dst[6] = c.z;  dst[7] = c.w;
    dst[8] = e.x;  dst[9] = e.y;  dst[10] = e.z; dst[11] = e.w;
    dst[12] = f.x; dst[13] = f.y; dst[14] = f.z; dst[15] = f.w;
}

// Kernel 2: 4-wave register-resident scan (r5-r7 key algebra), one flip per
// round, with (a) bare lgkmcnt-only barrier so row prefetches stay in
// flight across rounds, and (b) a 2-entry rotating prediction row cache
// (fresh prediction + previous prediction) so winners delayed by one flip
// still hit registers. sk = pos<<14 | i<<2 | (y+1); per elem per round:
// zj += d*w; cand = (sk | sign-mismatch-mask) - ck; key = min. Mismatch
// implies s=-y, so d=-2*y1 decodes wholly from the winning key.
__global__ __launch_bounds__(256) void hop_seq(const float* __restrict__ W,
                                               const float* __restrict__ x,
                                               const int* __restrict__ perms,
                                               const double* __restrict__ Z0,
                                               float* __restrict__ out) {
    const int b = blockIdx.x;
    const int tid = threadIdx.x;
    const int wid = tid >> 6;
    const int lane = tid & 63;

    __shared__ int wpos[N];        // 16 KB epoch-tagged inverse map
    __shared__ uint4 slot1v[2];    // per-wave min, parity buffered
    __shared__ uint4 slot2v[2];    // per-wave 2nd min, parity buffered

    // ---- register-resident field ----
    double zj[E];
    unsigned ymask[E];             // 0xFFFFFFFF if y>0 else 0x7FFFFFFF
    unsigned sk[E];
    {
        const double* __restrict__ zsrc = Z0 + (size_t)b * N + E * tid;
#pragma unroll
        for (int k = 0; k < E; ++k) zj[k] = zsrc[k];
        const float4* __restrict__ xs = (const float4*)(x + (size_t)b * N);
#pragma unroll
        for (int q = 0; q < 4; ++q) {
            const float4 xv = xs[4 * tid + q];
            ymask[4 * q + 0] = (xv.x > 0.f) ? 0xFFFFFFFFu : 0x7FFFFFFFu;
            ymask[4 * q + 1] = (xv.y > 0.f) ? 0xFFFFFFFFu : 0x7FFFFFFFu;
            ymask[4 * q + 2] = (xv.z > 0.f) ? 0xFFFFFFFFu : 0x7FFFFFFFu;
            ymask[4 * q + 3] = (xv.w > 0.f) ? 0xFFFFFFFFu : 0x7FFFFFFFu;
        }
    }
    const int* __restrict__ perm_b = perms + (size_t)b * T;

    float pfa[E], pfb[E];          // rotating prediction cache (W immutable)
    int pfa_i = -1, pfb_i = -1;
    unsigned r = 0;                // exchange parity counter (never reset)

    for (int base = 0; base < T; base += WIN) {
        const int epoch = (base >> 10) + 1;
        // scatter inverse map (window = permutation slice, indices distinct)
        const int4 iv = ((const int4*)(perm_b + base))[tid];
        wpos[iv.x] = (epoch << 10) | (4 * tid + 0);
        wpos[iv.y] = (epoch << 10) | (4 * tid + 1);
        wpos[iv.z] = (epoch << 10) | (4 * tid + 2);
        wpos[iv.w] = (epoch << 10) | (4 * tid + 3);
        __syncthreads();           // infrequent (40x): full drain acceptable
        // build static keys for the 16 owned elems
#pragma unroll
        for (int q = 0; q < 4; ++q) {
            const int4 wp = ((const int4*)wpos)[4 * tid + q];
            const int e0 = 4 * q;
            const unsigned i0 = (unsigned)(E * tid + e0);
            sk[e0 + 0] = ((wp.x >> 10) == epoch)
                ? (((unsigned)(wp.x & 1023) << 14) | ((i0 + 0) << 2) | ((ymask[e0 + 0] >> 30) & 2u)) : INFK;
            sk[e0 + 1] = ((wp.y >> 10) == epoch)
                ? (((unsigned)(wp.y & 1023) << 14) | ((i0 + 1) << 2) | ((ymask[e0 + 1] >> 30) & 2u)) : INFK;
            sk[e0 + 2] = ((wp.z >> 10) == epoch)
                ? (((unsigned)(wp.z & 1023) << 14) | ((i0 + 2) << 2) | ((ymask[e0 + 2] >> 30) & 2u)) : INFK;
            sk[e0 + 3] = ((wp.w >> 10) == epoch)
                ? (((unsigned)(wp.w & 1023) << 14) | ((i0 + 3) << 2) | ((ymask[e0 + 3] >> 30) & 2u)) : INFK;
        }

        unsigned ck = 0;
        // round-0 pure scan
        unsigned key = INFK;
#pragma unroll
        for (int k = 0; k < E; ++k) {
            const unsigned t2 = ((unsigned)__double2hiint(zj[k])) ^ ymask[k];
            const unsigned cand = (sk[k] | (unsigned)(((int)t2) >> 31)) - ck;
            key = umin2(key, cand);
        }

        for (;;) {
            // ---- wave min via DPP; publish; 2nd min; publish ----
            const unsigned m1 = wave_min64(key);
            const unsigned p = r & 1u; r++;
            if (lane == 0) ((unsigned*)&slot1v[p])[wid] = m1;
            const unsigned m2 = wave_min64((key == m1) ? INFK : key);
            if (lane == 0) ((unsigned*)&slot2v[p])[wid] = m2;
            BAR_LDS();   // LDS-only barrier: row prefetches stay in flight

            // ---- exact global top-2 from the 8 published values ----
            const uint4 s1 = slot1v[p];
            const unsigned g = umin2(umin2(s1.x, s1.y), umin2(s1.z, s1.w));
            if (g >= LIMIT) break;   // no valid future candidate (uniform)
            const uint4 s2 = slot2v[p];
            const unsigned o0 = (s1.x == g) ? s2.x : s1.x;
            const unsigned o1 = (s1.y == g) ? s2.y : s1.y;
            const unsigned o2 = (s1.z == g) ? s2.z : s1.z;
            const unsigned o3 = (s1.w == g) ? s2.w : s1.w;
            const unsigned g2 = umin2(umin2(o0, o1), umin2(o2, o3));

            const unsigned wk = g + ck;
            const int istar = (int)((wk >> 2) & 4095u);
            const int y1 = (int)(wk & 3u) - 1;
            const double d = (double)(-2 * y1);   // mismatch => s = -y
            const unsigned ck_old = ck;
            ck = ((wk >> 14) + 1u) << 14;

            // ---- winner fragment: cache hit (common) or direct load ----
            float wr[E];
            if (istar == pfa_i)      copy16(wr, pfa);
            else if (istar == pfb_i) copy16(wr, pfb);
            else                     load_row(W, istar, tid, wr);

            // ---- early prefetch of predicted next winner (rotates cache;
            //      issued ASAP so it has the whole rest of this round plus
            //      next round's reduce to complete under the bare barrier) ----
            if (g2 < LIMIT) {
                const int i2 = (int)(((g2 + ck_old) >> 2) & 4095u);
                if (i2 != pfa_i && i2 != pfb_i) {
                    copy16(pfb, pfa); pfb_i = pfa_i;
                    load_row(W, i2, tid, pfa); pfa_i = i2;
                }
            }

            // ---- owner fixup (1 thread) ----
            if (tid == (istar >> 4)) {
                const int kk = istar & 15;
#pragma unroll
                for (int k = 0; k < E; ++k)
                    if (k == kk) { ymask[k] ^= 0x80000000u; sk[k] ^= 2u; }
            }

            // ---- fused apply + scan for next winner ----
            key = INFK;
#pragma unroll
            for (int k = 0; k < E; ++k) {
                zj[k] += d * (double)wr[k];   // W[istar][istar]==0 -> owner safe
                const unsigned t2 = ((unsigned)__double2hiint(zj[k])) ^ ymask[k];
                const unsigned cand = (sk[k] | (unsigned)(((int)t2) >> 31)) - ck;
                key = umin2(key, cand);
            }
        }
    }

    // ---- output: y = +1 if ymask top bit set else -1 ----
    float4* __restrict__ os = (float4*)(out + (size_t)b * N);
#pragma unroll
    for (int q = 0; q < 4; ++q) {
        float4 o;
        o.x = (ymask[4 * q + 0] & 0x80000000u) ? 1.0f : -1.0f;
        o.y = (ymask[4 * q + 1] & 0x80000000u) ? 1.0f : -1.0f;
        o.z = (ymask[4 * q + 2] & 0x80000000u) ? 1.0f : -1.0f;
        o.w = (ymask[4 * q + 3] & 0x80000000u) ? 1.0f : -1.0f;
        os[4 * tid + q] = o;
    }
}

extern "C" void kernel_launch(void* const* d_in, const int* in_sizes, int n_in,
                              void* d_out, int out_size, void* d_ws, size_t ws_size,
                              hipStream_t stream) {
    const float* x = (const float*)d_in[0];      // [B, N] f32, bipolar
    const float* W = (const float*)d_in[1];      // [N, N] f32, symmetric, zero diag
    const int* perms = (const int*)d_in[2];      // [B, ITERS, N] i32
    float* out = (float*)d_out;                  // [B, N] f32
    double* Z0 = (double*)d_ws;                  // B*N doubles = 256 KB scratch

    hipLaunchKernelGGL(z0_gemv, dim3(N), dim3(256), 0, stream, W, x, Z0);
    hipLaunchKernelGGL(hop_seq, dim3(B), dim3(NT), 0, stream, W, x, perms, Z0, out);
}